// Round 2
// baseline (191.447 us; speedup 1.0000x reference)
//
#include <hip/hip_runtime.h>
#include <hip/hip_bf16.h>

#define C_DIM 64
#define N_TOK 4608
#define NBLK  72      // N_TOK / 64
#define B_SZ  2
#define MTILES 288    // N_TOK / 16

typedef __bf16 bf16x8 __attribute__((ext_vector_type(8)));
typedef float  f32x4  __attribute__((ext_vector_type(4)));

// ---------------------------------------------------------------------------
// Projection kernel (fp32 in, bf16 out):
//   q = (Wq x + bq) * (0.125*log2e)  -> qT[b][n][c]   (scale folded for exp2)
//   k = (Wk h + bk)                  -> kT[b][n][c]
//   v = (Wv h + bv)                  -> v [b][c][n]
// grid = B*NBLK blocks of 512 threads; each block does a 64-token slice.
// ---------------------------------------------------------------------------
__global__ __launch_bounds__(512) void proj_kernel(
    const float* __restrict__ x,  const float* __restrict__ h,
    const float* __restrict__ Wq, const float* __restrict__ bq,
    const float* __restrict__ Wk, const float* __restrict__ bk,
    const float* __restrict__ Wv, const float* __restrict__ bv,
    __hip_bfloat16* __restrict__ qT, __hip_bfloat16* __restrict__ kT,
    __hip_bfloat16* __restrict__ vO)
{
    __shared__ float xl[64 * 64];
    __shared__ float hl[64 * 64];
    __shared__ __hip_bfloat16 vl[64 * 64];

    const int b  = blockIdx.x / NBLK;
    const int n0 = (blockIdx.x % NBLK) * 64;
    const int t  = threadIdx.x;

    // stage x/h tiles [64 c][64 n]: 8 floats per thread, coalesced
    {
        const int c  = t >> 3;
        const int ns = (t & 7) * 8;
        *(float4*)(xl + c * 64 + ns) =
            *(const float4*)(x + (size_t)(b * C_DIM + c) * N_TOK + n0 + ns);
        *(float4*)(xl + c * 64 + ns + 4) =
            *(const float4*)(x + (size_t)(b * C_DIM + c) * N_TOK + n0 + ns + 4);
        *(float4*)(hl + c * 64 + ns) =
            *(const float4*)(h + (size_t)(b * C_DIM + c) * N_TOK + n0 + ns);
        *(float4*)(hl + c * 64 + ns + 4) =
            *(const float4*)(h + (size_t)(b * C_DIM + c) * N_TOK + n0 + ns + 4);
    }
    __syncthreads();

    const int n  = t & 63;          // token within tile
    const int ob = (t >> 6) * 8;    // 8 output channels per thread

    float acc[8];

    // ---- q ----
    {
        #pragma unroll
        for (int i = 0; i < 8; i++) acc[i] = bq[ob + i];
        for (int c = 0; c < 64; c++) {
            float xv = xl[c * 64 + n];
            #pragma unroll
            for (int i = 0; i < 8; i++) acc[i] += Wq[(ob + i) * 64 + c] * xv;
        }
        const float SC = 0.125f * 1.44269504088896f;  // 1/sqrt(C) * log2(e)
        union { __hip_bfloat16 e[8]; uint4 v; } o8;
        #pragma unroll
        for (int i = 0; i < 8; i++) o8.e[i] = __float2bfloat16(acc[i] * SC);
        *(uint4*)(qT + (size_t)(b * N_TOK + n0 + n) * 64 + ob) = o8.v;
    }

    // ---- k ----
    {
        #pragma unroll
        for (int i = 0; i < 8; i++) acc[i] = bk[ob + i];
        for (int c = 0; c < 64; c++) {
            float hv = hl[c * 64 + n];
            #pragma unroll
            for (int i = 0; i < 8; i++) acc[i] += Wk[(ob + i) * 64 + c] * hv;
        }
        union { __hip_bfloat16 e[8]; uint4 v; } o8;
        #pragma unroll
        for (int i = 0; i < 8; i++) o8.e[i] = __float2bfloat16(acc[i]);
        *(uint4*)(kT + (size_t)(b * N_TOK + n0 + n) * 64 + ob) = o8.v;
    }

    // ---- v (transpose through LDS so global write is coalesced [c][n]) ----
    {
        #pragma unroll
        for (int i = 0; i < 8; i++) acc[i] = bv[ob + i];
        for (int c = 0; c < 64; c++) {
            float hv = hl[c * 64 + n];
            #pragma unroll
            for (int i = 0; i < 8; i++) acc[i] += Wv[(ob + i) * 64 + c] * hv;
        }
        #pragma unroll
        for (int i = 0; i < 8; i++)
            vl[(ob + i) * 64 + n] = __float2bfloat16(acc[i]);
    }
    __syncthreads();
    {
        const int o  = t >> 3;
        const int ns = (t & 7) * 8;
        *(uint4*)(vO + (size_t)(b * C_DIM + o) * N_TOK + n0 + ns) =
            *(const uint4*)(vl + o * 64 + ns);
    }
}

// ---------------------------------------------------------------------------
// Flash attention, flash-decoding style. One block = 16 m-tokens; 4 waves
// each cover 1/4 of the n range (1152 tokens), then combine through LDS.
// S^T = K·Q trick: softmax stats are per-lane scalars (reduce over quads
// via 2 shfl_xor). grid = B*MTILES blocks of 256 threads.
// ---------------------------------------------------------------------------
__global__ __launch_bounds__(256) void attn_kernel(
    const __hip_bfloat16* __restrict__ qT,
    const __hip_bfloat16* __restrict__ kT,
    const __hip_bfloat16* __restrict__ vO,
    float* __restrict__ out)
{
    __shared__ __hip_bfloat16 plds[4 * 16 * 72];   // per-wave P tile, stride 72
    __shared__ float o_lds[4 * 16 * 72];           // per-wave O partial, stride 72
    __shared__ float mstat[4][16];
    __shared__ float lstat[4][16];

    const int b    = blockIdx.x / MTILES;
    const int mblk = blockIdx.x % MTILES;
    const int wave = threadIdx.x >> 6;
    const int lane = threadIdx.x & 63;
    const int col  = lane & 15;      // m (or c) within 16-tile
    const int quad = lane >> 4;
    const int m0   = mblk * 16;

    __hip_bfloat16* pw = plds + wave * (16 * 72);

    // loop-invariant Q B-fragments: B[k=c][n=m], c contiguous in qT[m][c]
    const __hip_bfloat16* qp = qT + (size_t)(b * N_TOK + m0 + col) * 64 + quad * 8;
    const bf16x8 qf0 = *(const bf16x8*)(qp);
    const bf16x8 qf1 = *(const bf16x8*)(qp + 32);

    const __hip_bfloat16* kbase = kT + (size_t)b * N_TOK * 64;
    const __hip_bfloat16* vbase = vO + (size_t)b * C_DIM * N_TOK;

    f32x4 accO[4];
    #pragma unroll
    for (int cc = 0; cc < 4; cc++) accO[cc] = (f32x4){0.f, 0.f, 0.f, 0.f};
    float rmax = -3.0e38f, rsum = 0.f;

    const int nbeg = wave * (N_TOK / 4);
    const int nend = nbeg + (N_TOK / 4);

    #pragma unroll 1
    for (int n0 = nbeg; n0 < nend; n0 += 64) {
        // ---- S^T tile: rows n (64), cols m (16) ----
        f32x4 s[4];
        #pragma unroll
        for (int j = 0; j < 4; j++) {
            const __hip_bfloat16* kp =
                kbase + (size_t)(n0 + j * 16 + col) * 64 + quad * 8;
            bf16x8 ka0 = *(const bf16x8*)(kp);
            bf16x8 ka1 = *(const bf16x8*)(kp + 32);
            s[j] = __builtin_amdgcn_mfma_f32_16x16x32_bf16(
                       ka0, qf0, (f32x4){0.f, 0.f, 0.f, 0.f}, 0, 0, 0);
            s[j] = __builtin_amdgcn_mfma_f32_16x16x32_bf16(ka1, qf1, s[j], 0, 0, 0);
        }

        // ---- online softmax over n (log2 domain; scale folded into q) ----
        float tm = s[0][0];
        #pragma unroll
        for (int j = 0; j < 4; j++)
            #pragma unroll
            for (int r = 0; r < 4; r++) tm = fmaxf(tm, s[j][r]);
        tm = fmaxf(tm, __shfl_xor(tm, 16));
        tm = fmaxf(tm, __shfl_xor(tm, 32));
        const float nmax  = fmaxf(rmax, tm);
        const float alpha = __builtin_amdgcn_exp2f(rmax - nmax);
        rmax = nmax;

        float pv[16];
        float psum = 0.f;
        #pragma unroll
        for (int j = 0; j < 4; j++)
            #pragma unroll
            for (int r = 0; r < 4; r++) {
                float e = __builtin_amdgcn_exp2f(s[j][r] - nmax);
                pv[j * 4 + r] = e;
                psum += e;
            }
        psum += __shfl_xor(psum, 16);
        psum += __shfl_xor(psum, 32);
        rsum = rsum * alpha + psum;

        #pragma unroll
        for (int cc = 0; cc < 4; cc++)
            #pragma unroll
            for (int r = 0; r < 4; r++) accO[cc][r] *= alpha;

        // ---- P -> LDS [m][n] (stride 72), 4 consecutive n per write ----
        #pragma unroll
        for (int j = 0; j < 4; j++) {
            union { __hip_bfloat16 e[4]; uint2 v; } pk;
            #pragma unroll
            for (int r = 0; r < 4; r++) pk.e[r] = __float2bfloat16(pv[j * 4 + r]);
            *(uint2*)(pw + col * 72 + j * 16 + quad * 4) = pk.v;
        }
        __asm__ volatile("s_waitcnt lgkmcnt(0)" ::: "memory");

        // ---- O^T += V · P^T  (per-wave, no barrier: own LDS region) ----
        const bf16x8 pb0 = *(const bf16x8*)(pw + col * 72 + quad * 8);
        const bf16x8 pb1 = *(const bf16x8*)(pw + col * 72 + 32 + quad * 8);
        #pragma unroll
        for (int cc = 0; cc < 4; cc++) {
            const __hip_bfloat16* vp =
                vbase + (size_t)(cc * 16 + col) * N_TOK + n0 + quad * 8;
            bf16x8 va0 = *(const bf16x8*)(vp);
            bf16x8 va1 = *(const bf16x8*)(vp + 32);
            accO[cc] = __builtin_amdgcn_mfma_f32_16x16x32_bf16(va0, pb0, accO[cc], 0, 0, 0);
            accO[cc] = __builtin_amdgcn_mfma_f32_16x16x32_bf16(va1, pb1, accO[cc], 0, 0, 0);
        }
    }

    // ---- write per-wave partials (unnormalized) to LDS ----
    #pragma unroll
    for (int cc = 0; cc < 4; cc++)
        *(f32x4*)(o_lds + (wave * 16 + col) * 72 + cc * 16 + quad * 4) = accO[cc];
    if (quad == 0) { mstat[wave][col] = rmax; lstat[wave][col] = rsum; }
    __syncthreads();

    // ---- combine 4 segments: lane (wave,quad,col) -> m=col, c=wave*16+quad*4+r
    {
        const float m01 = fmaxf(mstat[0][col], mstat[1][col]);
        const float m23 = fmaxf(mstat[2][col], mstat[3][col]);
        const float M   = fmaxf(m01, m23);
        float lsum = 0.f;
        f32x4 oacc = (f32x4){0.f, 0.f, 0.f, 0.f};
        #pragma unroll
        for (int sgm = 0; sgm < 4; sgm++) {
            const float w = __builtin_amdgcn_exp2f(mstat[sgm][col] - M);
            lsum += w * lstat[sgm][col];
            f32x4 ov = *(const f32x4*)(o_lds + (sgm * 16 + col) * 72 +
                                       wave * 16 + quad * 4);
            oacc += ov * w;
        }
        const float inv = 1.0f / lsum;
        #pragma unroll
        for (int r = 0; r < 4; r++) {
            const int c = wave * 16 + quad * 4 + r;
            out[(size_t)(b * C_DIM + c) * N_TOK + m0 + col] = oacc[r] * inv;
        }
    }
}

extern "C" void kernel_launch(void* const* d_in, const int* in_sizes, int n_in,
                              void* d_out, int out_size, void* d_ws, size_t ws_size,
                              hipStream_t stream) {
    const float* x  = (const float*)d_in[0];
    const float* h  = (const float*)d_in[1];
    const float* Wq = (const float*)d_in[2];
    const float* bq = (const float*)d_in[3];
    const float* Wk = (const float*)d_in[4];
    const float* bk = (const float*)d_in[5];
    const float* Wv = (const float*)d_in[6];
    const float* bv = (const float*)d_in[7];
    float* out = (float*)d_out;

    const size_t elems = (size_t)B_SZ * N_TOK * C_DIM;   // 589824
    __hip_bfloat16* qT = (__hip_bfloat16*)d_ws;
    __hip_bfloat16* kT = qT + elems;
    __hip_bfloat16* vO = kT + elems;

    proj_kernel<<<B_SZ * NBLK, 512, 0, stream>>>(x, h, Wq, bq, Wk, bk, Wv, bv,
                                                 qT, kT, vO);
    attn_kernel<<<B_SZ * MTILES, 256, 0, stream>>>(qT, kT, vO, out);
}

// Round 3
// 191.215 us; speedup vs baseline: 1.0012x; 1.0012x over previous
//
#include <hip/hip_runtime.h>
#include <hip/hip_bf16.h>

#define C_DIM 64
#define N_TOK 4608
#define NBLK  72       // N_TOK / 64
#define B_SZ  2
#define MTILES 288     // N_TOK / 16
#define NSEG  8        // n-segments == waves per attn block
#define SEGLEN (N_TOK / NSEG)   // 576

typedef __bf16 bf16x8 __attribute__((ext_vector_type(8)));
typedef float  f32x4  __attribute__((ext_vector_type(4)));

// ---------------------------------------------------------------------------
// Projection kernel (fp32 in, bf16 out):
//   q = (Wq x + bq) * (0.125*log2e)  -> qT[b][n][c]
//   k = (Wk h + bk)                  -> kT[b][n][c]
//   v = (Wv h + bv)                  -> v [b][c][n]
// Weights read via wave-uniform (readfirstlane) addresses -> SMEM s_load,
// killing the per-lane VMEM broadcast-load latency chain of round 2.
// ---------------------------------------------------------------------------
__global__ __launch_bounds__(512) void proj_kernel(
    const float* __restrict__ x,  const float* __restrict__ h,
    const float* __restrict__ Wq, const float* __restrict__ bq,
    const float* __restrict__ Wk, const float* __restrict__ bk,
    const float* __restrict__ Wv, const float* __restrict__ bv,
    __hip_bfloat16* __restrict__ qT, __hip_bfloat16* __restrict__ kT,
    __hip_bfloat16* __restrict__ vO)
{
    __shared__ float xl[64 * 64];
    __shared__ float hl[64 * 64];
    __shared__ __hip_bfloat16 vl[64 * 64];

    const int b  = blockIdx.x / NBLK;
    const int n0 = (blockIdx.x % NBLK) * 64;
    const int t  = threadIdx.x;

    {
        const int c  = t >> 3;
        const int ns = (t & 7) * 8;
        *(float4*)(xl + c * 64 + ns) =
            *(const float4*)(x + (size_t)(b * C_DIM + c) * N_TOK + n0 + ns);
        *(float4*)(xl + c * 64 + ns + 4) =
            *(const float4*)(x + (size_t)(b * C_DIM + c) * N_TOK + n0 + ns + 4);
        *(float4*)(hl + c * 64 + ns) =
            *(const float4*)(h + (size_t)(b * C_DIM + c) * N_TOK + n0 + ns);
        *(float4*)(hl + c * 64 + ns + 4) =
            *(const float4*)(h + (size_t)(b * C_DIM + c) * N_TOK + n0 + ns + 4);
    }
    __syncthreads();

    const int n   = t & 63;                                   // token
    const int obu = __builtin_amdgcn_readfirstlane((t >> 6) * 8); // 8 out ch

    float acc[8];

    // ---- q ----
    {
        const float* Wp = Wq + obu * 64;
        #pragma unroll
        for (int i = 0; i < 8; i++) acc[i] = bq[obu + i];
        for (int cb = 0; cb < 64; cb += 8) {
            float xv[8];
            #pragma unroll
            for (int j = 0; j < 8; j++) xv[j] = xl[(cb + j) * 64 + n];
            #pragma unroll
            for (int i = 0; i < 8; i++)
                #pragma unroll
                for (int j = 0; j < 8; j++)
                    acc[i] += Wp[i * 64 + cb + j] * xv[j];
        }
        const float SC = 0.125f * 1.44269504088896f;  // 1/sqrt(C) * log2(e)
        union { __hip_bfloat16 e[8]; uint4 v; } o8;
        #pragma unroll
        for (int i = 0; i < 8; i++) o8.e[i] = __float2bfloat16(acc[i] * SC);
        *(uint4*)(qT + (size_t)(b * N_TOK + n0 + n) * 64 + obu) = o8.v;
    }

    // ---- k ----
    {
        const float* Wp = Wk + obu * 64;
        #pragma unroll
        for (int i = 0; i < 8; i++) acc[i] = bk[obu + i];
        for (int cb = 0; cb < 64; cb += 8) {
            float hv[8];
            #pragma unroll
            for (int j = 0; j < 8; j++) hv[j] = hl[(cb + j) * 64 + n];
            #pragma unroll
            for (int i = 0; i < 8; i++)
                #pragma unroll
                for (int j = 0; j < 8; j++)
                    acc[i] += Wp[i * 64 + cb + j] * hv[j];
        }
        union { __hip_bfloat16 e[8]; uint4 v; } o8;
        #pragma unroll
        for (int i = 0; i < 8; i++) o8.e[i] = __float2bfloat16(acc[i]);
        *(uint4*)(kT + (size_t)(b * N_TOK + n0 + n) * 64 + obu) = o8.v;
    }

    // ---- v (transpose through LDS; global write coalesced [c][n]) ----
    {
        const float* Wp = Wv + obu * 64;
        #pragma unroll
        for (int i = 0; i < 8; i++) acc[i] = bv[obu + i];
        for (int cb = 0; cb < 64; cb += 8) {
            float hv[8];
            #pragma unroll
            for (int j = 0; j < 8; j++) hv[j] = hl[(cb + j) * 64 + n];
            #pragma unroll
            for (int i = 0; i < 8; i++)
                #pragma unroll
                for (int j = 0; j < 8; j++)
                    acc[i] += Wp[i * 64 + cb + j] * hv[j];
        }
        #pragma unroll
        for (int i = 0; i < 8; i++)
            vl[(obu + i) * 64 + n] = __float2bfloat16(acc[i]);
    }
    __syncthreads();
    {
        const int o  = t >> 3;
        const int ns = (t & 7) * 8;
        *(uint4*)(vO + (size_t)(b * C_DIM + o) * N_TOK + n0 + ns) =
            *(const uint4*)(vl + o * 64 + ns);
    }
}

// ---------------------------------------------------------------------------
// Flash attention, flash-decoding style. One block = one 16-m tile; 8 waves
// each cover 1/8 of the n range (576 tokens), combined in-block through LDS.
// S^T = K·Q trick keeps softmax stats per-lane (2 shfl_xor for max only;
// sum reduced across quads once after the loop). V loads issued at iteration
// top so the softmax chain hides their latency.
// ---------------------------------------------------------------------------
__global__ __launch_bounds__(512, 4) void attn_kernel(
    const __hip_bfloat16* __restrict__ qT,
    const __hip_bfloat16* __restrict__ kT,
    const __hip_bfloat16* __restrict__ vO,
    float* __restrict__ out)
{
    __shared__ __hip_bfloat16 plds[NSEG * 16 * 72];   // per-wave P tile
    __shared__ float o_lds[NSEG * 16 * 64];           // per-wave O partial
    __shared__ float mstat[NSEG][16];
    __shared__ float lstat[NSEG][16];

    const int b    = blockIdx.x / MTILES;
    const int mblk = blockIdx.x % MTILES;
    const int wave = threadIdx.x >> 6;
    const int lane = threadIdx.x & 63;
    const int col  = lane & 15;
    const int quad = lane >> 4;
    const int m0   = mblk * 16;

    __hip_bfloat16* pw = plds + wave * (16 * 72);

    // loop-invariant Q B-fragments
    const __hip_bfloat16* qp = qT + (size_t)(b * N_TOK + m0 + col) * 64 + quad * 8;
    const bf16x8 qf0 = *(const bf16x8*)(qp);
    const bf16x8 qf1 = *(const bf16x8*)(qp + 32);

    const __hip_bfloat16* kbase = kT + (size_t)b * N_TOK * 64;
    const __hip_bfloat16* vbase = vO + (size_t)b * C_DIM * N_TOK;

    f32x4 accO[4];
    #pragma unroll
    for (int cc = 0; cc < 4; cc++) accO[cc] = (f32x4){0.f, 0.f, 0.f, 0.f};
    float rmax = -3.0e38f, rsum = 0.f;

    const int nbeg = wave * SEGLEN;

    #pragma unroll 1
    for (int n0 = nbeg; n0 < nbeg + SEGLEN; n0 += 64) {
        // ---- V loads first: latency hidden behind softmax ----
        bf16x8 va[8];
        #pragma unroll
        for (int cc = 0; cc < 4; cc++) {
            const __hip_bfloat16* vp =
                vbase + (size_t)(cc * 16 + col) * N_TOK + n0 + quad * 8;
            va[2 * cc]     = *(const bf16x8*)(vp);
            va[2 * cc + 1] = *(const bf16x8*)(vp + 32);
        }

        // ---- S^T tile: rows n (64), cols m (16) ----
        f32x4 s[4];
        #pragma unroll
        for (int j = 0; j < 4; j++) {
            const __hip_bfloat16* kp =
                kbase + (size_t)(n0 + j * 16 + col) * 64 + quad * 8;
            bf16x8 ka0 = *(const bf16x8*)(kp);
            bf16x8 ka1 = *(const bf16x8*)(kp + 32);
            s[j] = __builtin_amdgcn_mfma_f32_16x16x32_bf16(
                       ka0, qf0, (f32x4){0.f, 0.f, 0.f, 0.f}, 0, 0, 0);
            s[j] = __builtin_amdgcn_mfma_f32_16x16x32_bf16(ka1, qf1, s[j], 0, 0, 0);
        }

        // ---- online softmax (log2 domain; scale folded into q) ----
        float tm = s[0][0];
        #pragma unroll
        for (int j = 0; j < 4; j++)
            #pragma unroll
            for (int r = 0; r < 4; r++) tm = fmaxf(tm, s[j][r]);
        tm = fmaxf(tm, __shfl_xor(tm, 16));
        tm = fmaxf(tm, __shfl_xor(tm, 32));
        const float nmax  = fmaxf(rmax, tm);
        const float alpha = __builtin_amdgcn_exp2f(rmax - nmax);
        rmax = nmax;

        float pv[16];
        float psum = 0.f;
        #pragma unroll
        for (int j = 0; j < 4; j++)
            #pragma unroll
            for (int r = 0; r < 4; r++) {
                float e = __builtin_amdgcn_exp2f(s[j][r] - nmax);
                pv[j * 4 + r] = e;
                psum += e;
            }
        rsum = rsum * alpha + psum;   // per-lane partial; quad-reduced at end

        #pragma unroll
        for (int cc = 0; cc < 4; cc++)
            #pragma unroll
            for (int r = 0; r < 4; r++) accO[cc][r] *= alpha;

        // ---- P -> LDS [m][n] (stride 72) ----
        #pragma unroll
        for (int j = 0; j < 4; j++) {
            union { __hip_bfloat16 e[4]; uint2 v; } pk;
            #pragma unroll
            for (int r = 0; r < 4; r++) pk.e[r] = __float2bfloat16(pv[j * 4 + r]);
            *(uint2*)(pw + col * 72 + j * 16 + quad * 4) = pk.v;
        }
        __asm__ volatile("s_waitcnt lgkmcnt(0)" ::: "memory");

        // ---- O^T += V · P^T ----
        const bf16x8 pb0 = *(const bf16x8*)(pw + col * 72 + quad * 8);
        const bf16x8 pb1 = *(const bf16x8*)(pw + col * 72 + 32 + quad * 8);
        #pragma unroll
        for (int cc = 0; cc < 4; cc++) {
            accO[cc] = __builtin_amdgcn_mfma_f32_16x16x32_bf16(va[2 * cc],     pb0, accO[cc], 0, 0, 0);
            accO[cc] = __builtin_amdgcn_mfma_f32_16x16x32_bf16(va[2 * cc + 1], pb1, accO[cc], 0, 0, 0);
        }
    }

    // ---- finalize per-wave stats, write partials ----
    rsum += __shfl_xor(rsum, 16);
    rsum += __shfl_xor(rsum, 32);
    #pragma unroll
    for (int cc = 0; cc < 4; cc++)
        *(f32x4*)(o_lds + (wave * 16 + col) * 64 + cc * 16 + quad * 4) = accO[cc];
    if (quad == 0) { mstat[wave][col] = rmax; lstat[wave][col] = rsum; }
    __syncthreads();

    // ---- combine 8 segments (first 256 threads) ----
    if (threadIdx.x < 256) {
        const int m  = threadIdx.x & 15;
        const int cq = threadIdx.x >> 4;   // 0..15 -> 4 channels each
        float M = -3.0e38f;
        #pragma unroll
        for (int sgm = 0; sgm < NSEG; sgm++) M = fmaxf(M, mstat[sgm][m]);
        float lsum = 0.f;
        f32x4 oacc = (f32x4){0.f, 0.f, 0.f, 0.f};
        #pragma unroll
        for (int sgm = 0; sgm < NSEG; sgm++) {
            const float w = __builtin_amdgcn_exp2f(mstat[sgm][m] - M);
            lsum += w * lstat[sgm][m];
            oacc += w * *(const f32x4*)(o_lds + (sgm * 16 + m) * 64 + cq * 4);
        }
        const float inv = 1.0f / lsum;
        #pragma unroll
        for (int r = 0; r < 4; r++) {
            const int c = cq * 4 + r;
            out[(size_t)(b * C_DIM + c) * N_TOK + m0 + m] = oacc[r] * inv;
        }
    }
}

extern "C" void kernel_launch(void* const* d_in, const int* in_sizes, int n_in,
                              void* d_out, int out_size, void* d_ws, size_t ws_size,
                              hipStream_t stream) {
    const float* x  = (const float*)d_in[0];
    const float* h  = (const float*)d_in[1];
    const float* Wq = (const float*)d_in[2];
    const float* bq = (const float*)d_in[3];
    const float* Wk = (const float*)d_in[4];
    const float* bk = (const float*)d_in[5];
    const float* Wv = (const float*)d_in[6];
    const float* bv = (const float*)d_in[7];
    float* out = (float*)d_out;

    const size_t elems = (size_t)B_SZ * N_TOK * C_DIM;   // 589824
    __hip_bfloat16* qT = (__hip_bfloat16*)d_ws;
    __hip_bfloat16* kT = qT + elems;
    __hip_bfloat16* vO = kT + elems;

    proj_kernel<<<B_SZ * NBLK, 512, 0, stream>>>(x, h, Wq, bq, Wk, bk, Wv, bv,
                                                 qT, kT, vO);
    attn_kernel<<<B_SZ * MTILES, 512, 0, stream>>>(qT, kT, vO, out);
}

// Round 4
// 129.143 us; speedup vs baseline: 1.4824x; 1.4807x over previous
//
#include <hip/hip_runtime.h>
#include <hip/hip_bf16.h>

#define C_DIM 64
#define N_TOK 4608
#define NBLK  72       // N_TOK / 64 (proj blocks per batch)
#define B_SZ  2
#define MBLKS 144      // N_TOK / 32 (attn m-blocks per batch)
#define NSEG  4        // n-segments (waves: 2 msub x 4 nseg)
#define SEGLEN (N_TOK / NSEG)   // 1152
#define KTILES (N_TOK / 16)     // 288
#define VTILES (N_TOK / 64)     // 72

typedef __bf16 bf16x8 __attribute__((ext_vector_type(8)));
typedef float  f32x4  __attribute__((ext_vector_type(4)));

// ---------------------------------------------------------------------------
// K swizzled layout: kS[b][ntile16][half][quad][col][8e]
//   element (b,n,c): ntile=n>>4, half=c>>5, quad=(c>>3)&3, col=n&15, e=c&7
//   -> an MFMA A-fragment load is base + lane*8 elems (contiguous 1KB/wave)
// V swizzled layout: vS[b][ntile64][cc][half][quad][col][8e]
//   element (b,c,n): ntile=n>>6, cc=c>>4, col=c&15, half=(n>>5)&1,
//                    quad=(n>>3)&3, e=n&7
// ---------------------------------------------------------------------------

__global__ __launch_bounds__(512) void proj_kernel(
    const float* __restrict__ x,  const float* __restrict__ h,
    const float* __restrict__ Wq, const float* __restrict__ bq,
    const float* __restrict__ Wk, const float* __restrict__ bk,
    const float* __restrict__ Wv, const float* __restrict__ bv,
    __hip_bfloat16* __restrict__ qT, __hip_bfloat16* __restrict__ kS,
    __hip_bfloat16* __restrict__ vS)
{
    __shared__ float xl[64 * 64];
    __shared__ float hl[64 * 64];
    __shared__ __hip_bfloat16 vl[64 * 64];

    const int b  = blockIdx.x / NBLK;
    const int n0 = (blockIdx.x % NBLK) * 64;
    const int t  = threadIdx.x;

    {
        const int c  = t >> 3;
        const int ns = (t & 7) * 8;
        *(float4*)(xl + c * 64 + ns) =
            *(const float4*)(x + (size_t)(b * C_DIM + c) * N_TOK + n0 + ns);
        *(float4*)(xl + c * 64 + ns + 4) =
            *(const float4*)(x + (size_t)(b * C_DIM + c) * N_TOK + n0 + ns + 4);
        *(float4*)(hl + c * 64 + ns) =
            *(const float4*)(h + (size_t)(b * C_DIM + c) * N_TOK + n0 + ns);
        *(float4*)(hl + c * 64 + ns + 4) =
            *(const float4*)(h + (size_t)(b * C_DIM + c) * N_TOK + n0 + ns + 4);
    }
    __syncthreads();

    const int n   = t & 63;                                       // token
    const int obu = __builtin_amdgcn_readfirstlane((t >> 6) * 8); // 8 out ch

    float acc[8];

    // ---- q  -> qT[b][n][c] (linear; read once per attn wave) ----
    {
        const float* Wp = Wq + obu * 64;
        #pragma unroll
        for (int i = 0; i < 8; i++) acc[i] = bq[obu + i];
        for (int cb = 0; cb < 64; cb += 8) {
            float xv[8];
            #pragma unroll
            for (int j = 0; j < 8; j++) xv[j] = xl[(cb + j) * 64 + n];
            #pragma unroll
            for (int i = 0; i < 8; i++)
                #pragma unroll
                for (int j = 0; j < 8; j++)
                    acc[i] += Wp[i * 64 + cb + j] * xv[j];
        }
        const float SC = 0.125f * 1.44269504088896f;  // 1/sqrt(C) * log2(e)
        union { __hip_bfloat16 e[8]; uint4 v; } o8;
        #pragma unroll
        for (int i = 0; i < 8; i++) o8.e[i] = __float2bfloat16(acc[i] * SC);
        *(uint4*)(qT + (size_t)(b * N_TOK + n0 + n) * 64 + obu) = o8.v;
    }

    // ---- k -> swizzled kS (thread's 8 channels are exactly one 16B chunk) --
    {
        const float* Wp = Wk + obu * 64;
        #pragma unroll
        for (int i = 0; i < 8; i++) acc[i] = bk[obu + i];
        for (int cb = 0; cb < 64; cb += 8) {
            float hv[8];
            #pragma unroll
            for (int j = 0; j < 8; j++) hv[j] = hl[(cb + j) * 64 + n];
            #pragma unroll
            for (int i = 0; i < 8; i++)
                #pragma unroll
                for (int j = 0; j < 8; j++)
                    acc[i] += Wp[i * 64 + cb + j] * hv[j];
        }
        union { __hip_bfloat16 e[8]; uint4 v; } o8;
        #pragma unroll
        for (int i = 0; i < 8; i++) o8.e[i] = __float2bfloat16(acc[i]);
        const size_t off = (((size_t)b * KTILES + (n0 >> 4) + (n >> 4)) << 10)
                         + (obu >> 5) * 512 + ((obu >> 3) & 3) * 128
                         + (n & 15) * 8;
        *(uint4*)(kS + off) = o8.v;
    }

    // ---- v (LDS transpose, then gather into swizzled vS, coalesced) ----
    {
        const float* Wp = Wv + obu * 64;
        #pragma unroll
        for (int i = 0; i < 8; i++) acc[i] = bv[obu + i];
        for (int cb = 0; cb < 64; cb += 8) {
            float hv[8];
            #pragma unroll
            for (int j = 0; j < 8; j++) hv[j] = hl[(cb + j) * 64 + n];
            #pragma unroll
            for (int i = 0; i < 8; i++)
                #pragma unroll
                for (int j = 0; j < 8; j++)
                    acc[i] += Wp[i * 64 + cb + j] * hv[j];
        }
        #pragma unroll
        for (int i = 0; i < 8; i++)
            vl[(obu + i) * 64 + n] = __float2bfloat16(acc[i]);
    }
    __syncthreads();
    {
        // thread t owns swizzled chunk t: cc=t>>7, half=(t>>6)&1,
        // quad=(t>>4)&3, col=t&15 -> c=cc*16+col, nlo=half*32+quad*8
        const int cc   = t >> 7;
        const int half = (t >> 6) & 1;
        const int qd   = (t >> 4) & 3;
        const int col2 = t & 15;
        const size_t vbase = ((size_t)(b * VTILES) + (n0 >> 6)) << 12;
        *(uint4*)(vS + vbase + (size_t)t * 8) =
            *(const uint4*)(vl + (cc * 16 + col2) * 64 + half * 32 + qd * 8);
    }
}

// ---------------------------------------------------------------------------
// Flash attention. Block = 32 m-tokens; 8 waves = 2 m-subtiles x 4 n-segments
// (1152 n each), combined in-block through LDS. All K/V fragment loads are
// contiguous 1KB/wave thanks to the swizzled layouts. S^T=K.Q trick keeps
// softmax per-lane. grid = B*MBLKS blocks of 512 threads.
// ---------------------------------------------------------------------------
__global__ __launch_bounds__(512, 4) void attn_kernel(
    const __hip_bfloat16* __restrict__ qT,
    const __hip_bfloat16* __restrict__ kS,
    const __hip_bfloat16* __restrict__ vS,
    float* __restrict__ out)
{
    __shared__ __hip_bfloat16 plds[8 * 16 * 72];     // per-wave P tile
    __shared__ float o_lds[NSEG * 32 * 64];          // per-segment O partials
    __shared__ float mstat[NSEG][32];
    __shared__ float lstat[NSEG][32];

    const int b    = blockIdx.x / MBLKS;
    const int mblk = blockIdx.x % MBLKS;
    const int wave = threadIdx.x >> 6;
    const int lane = threadIdx.x & 63;
    const int col  = lane & 15;
    const int quad = lane >> 4;
    const int msub = wave & 1;
    const int nsub = wave >> 1;
    const int m0   = mblk * 32 + msub * 16;

    __hip_bfloat16* pw = plds + wave * (16 * 72);

    // loop-invariant Q B-fragments (one-time scatter, irrelevant)
    const __hip_bfloat16* qp = qT + (size_t)(b * N_TOK + m0 + col) * 64 + quad * 8;
    const bf16x8 qf0 = *(const bf16x8*)(qp);
    const bf16x8 qf1 = *(const bf16x8*)(qp + 32);

    f32x4 accO[4];
    #pragma unroll
    for (int cc = 0; cc < 4; cc++) accO[cc] = (f32x4){0.f, 0.f, 0.f, 0.f};
    float rmax = -3.0e38f, rsum = 0.f;

    const int nbeg = nsub * SEGLEN;

    #pragma unroll 1
    for (int n0 = nbeg; n0 < nbeg + SEGLEN; n0 += 64) {
        // ---- V fragment loads first (contiguous 1KB/wave each pair) ----
        const __hip_bfloat16* vt =
            vS + ((((size_t)b * VTILES) + (n0 >> 6)) << 12) + lane * 8;
        bf16x8 va[8];
        #pragma unroll
        for (int cc = 0; cc < 4; cc++) {
            va[2 * cc]     = *(const bf16x8*)(vt + cc * 1024);
            va[2 * cc + 1] = *(const bf16x8*)(vt + cc * 1024 + 512);
        }

        // ---- S^T tile: rows n (64), cols m (16); contiguous K loads ----
        const __hip_bfloat16* kt =
            kS + (((size_t)b * KTILES + (n0 >> 4)) << 10) + lane * 8;
        f32x4 s[4];
        #pragma unroll
        for (int j = 0; j < 4; j++) {
            bf16x8 ka0 = *(const bf16x8*)(kt + (j << 10));
            bf16x8 ka1 = *(const bf16x8*)(kt + (j << 10) + 512);
            s[j] = __builtin_amdgcn_mfma_f32_16x16x32_bf16(
                       ka0, qf0, (f32x4){0.f, 0.f, 0.f, 0.f}, 0, 0, 0);
            s[j] = __builtin_amdgcn_mfma_f32_16x16x32_bf16(ka1, qf1, s[j], 0, 0, 0);
        }

        // ---- online softmax (log2 domain; scale folded into q) ----
        float tm = s[0][0];
        #pragma unroll
        for (int j = 0; j < 4; j++)
            #pragma unroll
            for (int r = 0; r < 4; r++) tm = fmaxf(tm, s[j][r]);
        tm = fmaxf(tm, __shfl_xor(tm, 16));
        tm = fmaxf(tm, __shfl_xor(tm, 32));
        const float nmax  = fmaxf(rmax, tm);
        const float alpha = __builtin_amdgcn_exp2f(rmax - nmax);
        rmax = nmax;

        float pv[16];
        float psum = 0.f;
        #pragma unroll
        for (int j = 0; j < 4; j++)
            #pragma unroll
            for (int r = 0; r < 4; r++) {
                float e = __builtin_amdgcn_exp2f(s[j][r] - nmax);
                pv[j * 4 + r] = e;
                psum += e;
            }
        rsum = rsum * alpha + psum;   // per-lane partial; quad-reduced at end

        #pragma unroll
        for (int cc = 0; cc < 4; cc++)
            #pragma unroll
            for (int r = 0; r < 4; r++) accO[cc][r] *= alpha;

        // ---- P -> LDS [m][n] (stride 72) ----
        #pragma unroll
        for (int j = 0; j < 4; j++) {
            union { __hip_bfloat16 e[4]; uint2 v; } pk;
            #pragma unroll
            for (int r = 0; r < 4; r++) pk.e[r] = __float2bfloat16(pv[j * 4 + r]);
            *(uint2*)(pw + col * 72 + j * 16 + quad * 4) = pk.v;
        }
        __asm__ volatile("s_waitcnt lgkmcnt(0)" ::: "memory");

        // ---- O^T += V . P^T ----
        const bf16x8 pb0 = *(const bf16x8*)(pw + col * 72 + quad * 8);
        const bf16x8 pb1 = *(const bf16x8*)(pw + col * 72 + 32 + quad * 8);
        #pragma unroll
        for (int cc = 0; cc < 4; cc++) {
            accO[cc] = __builtin_amdgcn_mfma_f32_16x16x32_bf16(va[2 * cc],     pb0, accO[cc], 0, 0, 0);
            accO[cc] = __builtin_amdgcn_mfma_f32_16x16x32_bf16(va[2 * cc + 1], pb1, accO[cc], 0, 0, 0);
        }
    }

    // ---- finalize per-wave stats, write partials ----
    rsum += __shfl_xor(rsum, 16);
    rsum += __shfl_xor(rsum, 32);
    #pragma unroll
    for (int cc = 0; cc < 4; cc++)
        *(f32x4*)(o_lds + (size_t)(nsub * 32 + msub * 16 + col) * 64 +
                  cc * 16 + quad * 4) = accO[cc];
    if (quad == 0) {
        mstat[nsub][msub * 16 + col] = rmax;
        lstat[nsub][msub * 16 + col] = rsum;
    }
    __syncthreads();

    // ---- combine 4 segments: 512 threads = 32 m x 16 c-quads ----
    {
        const int m  = threadIdx.x & 31;
        const int cq = threadIdx.x >> 5;
        float M = -3.0e38f;
        #pragma unroll
        for (int sgm = 0; sgm < NSEG; sgm++) M = fmaxf(M, mstat[sgm][m]);
        float lsum = 0.f;
        f32x4 oacc = (f32x4){0.f, 0.f, 0.f, 0.f};
        #pragma unroll
        for (int sgm = 0; sgm < NSEG; sgm++) {
            const float w = __builtin_amdgcn_exp2f(mstat[sgm][m] - M);
            lsum += w * lstat[sgm][m];
            oacc += w * *(const f32x4*)(o_lds + (size_t)(sgm * 32 + m) * 64 + cq * 4);
        }
        const float inv = 1.0f / lsum;
        #pragma unroll
        for (int r = 0; r < 4; r++) {
            const int c = cq * 4 + r;
            out[(size_t)(b * C_DIM + c) * N_TOK + mblk * 32 + m] = oacc[r] * inv;
        }
    }
}

extern "C" void kernel_launch(void* const* d_in, const int* in_sizes, int n_in,
                              void* d_out, int out_size, void* d_ws, size_t ws_size,
                              hipStream_t stream) {
    const float* x  = (const float*)d_in[0];
    const float* h  = (const float*)d_in[1];
    const float* Wq = (const float*)d_in[2];
    const float* bq = (const float*)d_in[3];
    const float* Wk = (const float*)d_in[4];
    const float* bk = (const float*)d_in[5];
    const float* Wv = (const float*)d_in[6];
    const float* bv = (const float*)d_in[7];
    float* out = (float*)d_out;

    const size_t elems = (size_t)B_SZ * N_TOK * C_DIM;   // 589824
    __hip_bfloat16* qT = (__hip_bfloat16*)d_ws;
    __hip_bfloat16* kS = qT + elems;
    __hip_bfloat16* vS = kS + elems;

    proj_kernel<<<B_SZ * NBLK, 512, 0, stream>>>(x, h, Wq, bq, Wk, bk, Wv, bv,
                                                 qT, kS, vS);
    attn_kernel<<<B_SZ * MBLKS, 512, 0, stream>>>(qT, kS, vS, out);
}

// Round 5
// 106.640 us; speedup vs baseline: 1.7953x; 1.2110x over previous
//
#include <hip/hip_runtime.h>
#include <hip/hip_bf16.h>

#define C_DIM 64
#define N_TOK 4608
#define NBLK  72       // proj blocks per batch (64 tokens each)
#define B_SZ  2
#define MTILES 288     // attn m-blocks per batch (16 m-tokens each)
#define NSEG  8        // n-segments == waves per attn block
#define SEGLEN (N_TOK / NSEG)   // 576
#define KTILES 288     // N_TOK/16 swizzled 16-token K/Q tiles per batch
#define VTILES 72      // N_TOK/64 swizzled 64-token V tiles per batch

typedef __bf16 bf16x8 __attribute__((ext_vector_type(8)));
typedef float  f32x4  __attribute__((ext_vector_type(4)));

// ---------------------------------------------------------------------------
// Swizzled fragment layouts (16B-chunk granular, contiguous 1KB wave loads):
//  qS/kS: [b][ntile16][half=c>>5][quad=(c>>3)&3][col=n&15][e=c&7]
//  vS:    [b][ntile64][cc=c>>4][half=(n>>5)&1][quad=(n>>3)&3][col=c&15][e=n&7]
// ---------------------------------------------------------------------------

// GEMM tile helper: D[4 otiles][16x16] = W(LDS) . B + bias
__device__ __forceinline__ void gemm_tile(
    const __hip_bfloat16* wmat, const bf16x8 bin[2], const float* bias,
    int col, int quad, f32x4 acc[4])
{
    #pragma unroll
    for (int ot = 0; ot < 4; ot++) {
        f32x4 a = (f32x4){0.f, 0.f, 0.f, 0.f};
        #pragma unroll
        for (int kh = 0; kh < 2; kh++) {
            bf16x8 wf = *(const bf16x8*)(wmat + (ot * 16 + col) * 72 +
                                         kh * 32 + quad * 8);
            a = __builtin_amdgcn_mfma_f32_16x16x32_bf16(wf, bin[kh], a, 0, 0, 0);
        }
        float4 b4 = *(const float4*)(bias + ot * 16 + quad * 4);
        a[0] += b4.x; a[1] += b4.y; a[2] += b4.z; a[3] += b4.w;
        acc[ot] = a;
    }
}

// store D tile into the qS/kS swizzled layout (coalesced uint2 stores)
__device__ __forceinline__ void store_swz(
    __hip_bfloat16* dst, const f32x4 acc[4], int col, int quad, float sc)
{
    #pragma unroll
    for (int ot = 0; ot < 4; ot++) {
        union { __hip_bfloat16 e[4]; uint2 v; } pk;
        #pragma unroll
        for (int r = 0; r < 4; r++) pk.e[r] = __float2bfloat16(acc[ot][r] * sc);
        *(uint2*)(dst + (ot >> 1) * 512 + ((ot * 2 + (quad >> 1)) & 3) * 128 +
                  col * 8 + (quad & 1) * 4) = pk.v;
    }
}

// ---------------------------------------------------------------------------
// MFMA projection kernel. Block = 256 threads (4 waves), 64 tokens.
// All weight/input operands flow LDS->VGPR (ds_read_b128); zero SMEM
// dependence in the hot path (round-4 proj was lgkm/SGPR-latency-bound).
// ---------------------------------------------------------------------------
__global__ __launch_bounds__(256) void proj_kernel(
    const float* __restrict__ x,  const float* __restrict__ h,
    const float* __restrict__ Wq, const float* __restrict__ bq,
    const float* __restrict__ Wk, const float* __restrict__ bk,
    const float* __restrict__ Wv, const float* __restrict__ bv,
    __hip_bfloat16* __restrict__ qS, __hip_bfloat16* __restrict__ kS,
    __hip_bfloat16* __restrict__ vS)
{
    __shared__ __hip_bfloat16 wl[3 * 64 * 72];   // Wq,Wk,Wv bf16 [o][c] pad72
    __shared__ __hip_bfloat16 xt[64 * 72];       // x^T bf16 [n][c] pad72
    __shared__ __hip_bfloat16 ht[64 * 72];       // h^T bf16 [n][c] pad72
    __shared__ __hip_bfloat16 vl[64 * 72];       // v staging [c][n] pad72

    const int b  = blockIdx.x / NBLK;
    const int n0 = (blockIdx.x % NBLK) * 64;
    const int t  = threadIdx.x;

    // ---- stage weights (fp32 global coalesced -> bf16 LDS) ----
    #pragma unroll
    for (int mat = 0; mat < 3; mat++) {
        const float* W = (mat == 0) ? Wq : ((mat == 1) ? Wk : Wv);
        __hip_bfloat16* wd = wl + mat * (64 * 72);
        #pragma unroll
        for (int i = 0; i < 16; i++) {
            const int idx = i * 256 + t;
            wd[(idx >> 6) * 72 + (idx & 63)] = __float2bfloat16(W[idx]);
        }
    }
    // ---- stage x,h transposed ([c][n] global -> [n][c] LDS) ----
    #pragma unroll
    for (int i = 0; i < 16; i++) {
        const int idx = i * 256 + t;
        const int c = idx >> 6, n = idx & 63;
        xt[n * 72 + c] = __float2bfloat16(x[(size_t)(b * C_DIM + c) * N_TOK + n0 + n]);
        ht[n * 72 + c] = __float2bfloat16(h[(size_t)(b * C_DIM + c) * N_TOK + n0 + n]);
    }
    __syncthreads();

    const int wave = t >> 6, lane = t & 63;
    const int col = lane & 15, quad = lane >> 4;

    // B-operand fragments: B[k=c][n=token], token = wave*16+col
    bf16x8 xb[2], hb[2];
    #pragma unroll
    for (int kh = 0; kh < 2; kh++) {
        xb[kh] = *(const bf16x8*)(xt + (wave * 16 + col) * 72 + kh * 32 + quad * 8);
        hb[kh] = *(const bf16x8*)(ht + (wave * 16 + col) * 72 + kh * 32 + quad * 8);
    }

    const size_t tile16 = (size_t)b * KTILES + (n0 >> 4) + wave;
    f32x4 acc[4];

    // ---- q = (Wq x + bq) * SC -> qS swizzled ----
    gemm_tile(wl + 0 * (64 * 72), xb, bq, col, quad, acc);
    store_swz(qS + (tile16 << 10), acc, col, quad, 0.125f * 1.44269504088896f);

    // ---- k = Wk h + bk -> kS swizzled ----
    gemm_tile(wl + 1 * (64 * 72), hb, bk, col, quad, acc);
    store_swz(kS + (tile16 << 10), acc, col, quad, 1.0f);

    // ---- v = Wv h + bv -> vl LDS [c][n], then swizzle-gather ----
    gemm_tile(wl + 2 * (64 * 72), hb, bv, col, quad, acc);
    #pragma unroll
    for (int ot = 0; ot < 4; ot++)
        #pragma unroll
        for (int r = 0; r < 4; r++)
            vl[(ot * 16 + quad * 4 + r) * 72 + wave * 16 + col] =
                __float2bfloat16(acc[ot][r]);
    __syncthreads();
    {
        const size_t vbase = ((size_t)(b * VTILES) + (n0 >> 6)) << 12;
        #pragma unroll
        for (int rep = 0; rep < 2; rep++) {
            const int ch = rep * 256 + t;        // 512 chunks of 8 elements
            const int cc = ch >> 7, hf = (ch >> 6) & 1;
            const int qd = (ch >> 4) & 3, c2 = ch & 15;
            *(uint4*)(vS + vbase + (size_t)ch * 8) =
                *(const uint4*)(vl + (cc * 16 + c2) * 72 + hf * 32 + qd * 8);
        }
    }
}

// ---------------------------------------------------------------------------
// Flash attention. Block = 16 m-tokens, 8 waves each covering 576 n-tokens,
// combined in-block through LDS. All K/V/Q fragment loads contiguous
// (swizzled layouts). grid = B*MTILES blocks of 512 threads.
// ---------------------------------------------------------------------------
__global__ __launch_bounds__(512, 4) void attn_kernel(
    const __hip_bfloat16* __restrict__ qS,
    const __hip_bfloat16* __restrict__ kS,
    const __hip_bfloat16* __restrict__ vS,
    float* __restrict__ out)
{
    __shared__ __hip_bfloat16 plds[NSEG * 16 * 72];   // per-wave P tile
    __shared__ float o_lds[NSEG * 16 * 64];           // per-wave O partial
    __shared__ float mstat[NSEG][16];
    __shared__ float lstat[NSEG][16];

    const int b    = blockIdx.x / MTILES;
    const int mblk = blockIdx.x % MTILES;
    const int wave = threadIdx.x >> 6;
    const int lane = threadIdx.x & 63;
    const int col  = lane & 15;
    const int quad = lane >> 4;
    const int m0   = mblk * 16;

    __hip_bfloat16* pw = plds + wave * (16 * 72);

    // loop-invariant Q B-fragments: contiguous 1KB wave load from qS
    const __hip_bfloat16* qp =
        qS + (((size_t)b * KTILES + (m0 >> 4)) << 10) + lane * 8;
    const bf16x8 qf0 = *(const bf16x8*)(qp);
    const bf16x8 qf1 = *(const bf16x8*)(qp + 512);

    f32x4 accO[4];
    #pragma unroll
    for (int cc = 0; cc < 4; cc++) accO[cc] = (f32x4){0.f, 0.f, 0.f, 0.f};
    float rmax = -3.0e38f, rsum = 0.f;

    const int nbeg = wave * SEGLEN;

    #pragma unroll 1
    for (int n0 = nbeg; n0 < nbeg + SEGLEN; n0 += 64) {
        // ---- V fragment loads first: latency hidden behind QK+softmax ----
        const __hip_bfloat16* vt =
            vS + ((((size_t)b * VTILES) + (n0 >> 6)) << 12) + lane * 8;
        bf16x8 va[8];
        #pragma unroll
        for (int cc = 0; cc < 4; cc++) {
            va[2 * cc]     = *(const bf16x8*)(vt + cc * 1024);
            va[2 * cc + 1] = *(const bf16x8*)(vt + cc * 1024 + 512);
        }

        // ---- S^T tile: rows n (64), cols m (16); contiguous K loads ----
        const __hip_bfloat16* kt =
            kS + (((size_t)b * KTILES + (n0 >> 4)) << 10) + lane * 8;
        f32x4 s[4];
        #pragma unroll
        for (int j = 0; j < 4; j++) {
            bf16x8 ka0 = *(const bf16x8*)(kt + (j << 10));
            bf16x8 ka1 = *(const bf16x8*)(kt + (j << 10) + 512);
            s[j] = __builtin_amdgcn_mfma_f32_16x16x32_bf16(
                       ka0, qf0, (f32x4){0.f, 0.f, 0.f, 0.f}, 0, 0, 0);
            s[j] = __builtin_amdgcn_mfma_f32_16x16x32_bf16(ka1, qf1, s[j], 0, 0, 0);
        }

        // ---- online softmax (log2 domain; scale folded into q) ----
        float tm = s[0][0];
        #pragma unroll
        for (int j = 0; j < 4; j++)
            #pragma unroll
            for (int r = 0; r < 4; r++) tm = fmaxf(tm, s[j][r]);
        tm = fmaxf(tm, __shfl_xor(tm, 16));
        tm = fmaxf(tm, __shfl_xor(tm, 32));
        const float nmax  = fmaxf(rmax, tm);
        const float alpha = __builtin_amdgcn_exp2f(rmax - nmax);
        rmax = nmax;

        float pv[16];
        float psum = 0.f;
        #pragma unroll
        for (int j = 0; j < 4; j++)
            #pragma unroll
            for (int r = 0; r < 4; r++) {
                float e = __builtin_amdgcn_exp2f(s[j][r] - nmax);
                pv[j * 4 + r] = e;
                psum += e;
            }
        rsum = rsum * alpha + psum;   // per-lane partial; quad-reduced at end

        #pragma unroll
        for (int cc = 0; cc < 4; cc++)
            #pragma unroll
            for (int r = 0; r < 4; r++) accO[cc][r] *= alpha;

        // ---- P -> LDS [m][n] (stride 72) ----
        #pragma unroll
        for (int j = 0; j < 4; j++) {
            union { __hip_bfloat16 e[4]; uint2 v; } pk;
            #pragma unroll
            for (int r = 0; r < 4; r++) pk.e[r] = __float2bfloat16(pv[j * 4 + r]);
            *(uint2*)(pw + col * 72 + j * 16 + quad * 4) = pk.v;
        }
        __asm__ volatile("s_waitcnt lgkmcnt(0)" ::: "memory");

        // ---- O^T += V . P^T ----
        const bf16x8 pb0 = *(const bf16x8*)(pw + col * 72 + quad * 8);
        const bf16x8 pb1 = *(const bf16x8*)(pw + col * 72 + 32 + quad * 8);
        #pragma unroll
        for (int cc = 0; cc < 4; cc++) {
            accO[cc] = __builtin_amdgcn_mfma_f32_16x16x32_bf16(va[2 * cc],     pb0, accO[cc], 0, 0, 0);
            accO[cc] = __builtin_amdgcn_mfma_f32_16x16x32_bf16(va[2 * cc + 1], pb1, accO[cc], 0, 0, 0);
        }
    }

    // ---- finalize per-wave stats, write partials ----
    rsum += __shfl_xor(rsum, 16);
    rsum += __shfl_xor(rsum, 32);
    #pragma unroll
    for (int cc = 0; cc < 4; cc++)
        *(f32x4*)(o_lds + (wave * 16 + col) * 64 + cc * 16 + quad * 4) = accO[cc];
    if (quad == 0) { mstat[wave][col] = rmax; lstat[wave][col] = rsum; }
    __syncthreads();

    // ---- combine 8 segments (first 256 threads) ----
    if (threadIdx.x < 256) {
        const int m  = threadIdx.x & 15;
        const int cq = threadIdx.x >> 4;   // 0..15 -> 4 channels each
        float M = -3.0e38f;
        #pragma unroll
        for (int sgm = 0; sgm < NSEG; sgm++) M = fmaxf(M, mstat[sgm][m]);
        float lsum = 0.f;
        f32x4 oacc = (f32x4){0.f, 0.f, 0.f, 0.f};
        #pragma unroll
        for (int sgm = 0; sgm < NSEG; sgm++) {
            const float w = __builtin_amdgcn_exp2f(mstat[sgm][m] - M);
            lsum += w * lstat[sgm][m];
            oacc += w * *(const f32x4*)(o_lds + (sgm * 16 + m) * 64 + cq * 4);
        }
        const float inv = 1.0f / lsum;
        #pragma unroll
        for (int r = 0; r < 4; r++) {
            const int c = cq * 4 + r;
            out[(size_t)(b * C_DIM + c) * N_TOK + m0 + m] = oacc[r] * inv;
        }
    }
}

extern "C" void kernel_launch(void* const* d_in, const int* in_sizes, int n_in,
                              void* d_out, int out_size, void* d_ws, size_t ws_size,
                              hipStream_t stream) {
    const float* x  = (const float*)d_in[0];
    const float* h  = (const float*)d_in[1];
    const float* Wq = (const float*)d_in[2];
    const float* bq = (const float*)d_in[3];
    const float* Wk = (const float*)d_in[4];
    const float* bk = (const float*)d_in[5];
    const float* Wv = (const float*)d_in[6];
    const float* bv = (const float*)d_in[7];
    float* out = (float*)d_out;

    const size_t elems = (size_t)B_SZ * N_TOK * C_DIM;   // 589824
    __hip_bfloat16* qS = (__hip_bfloat16*)d_ws;
    __hip_bfloat16* kS = qS + elems;
    __hip_bfloat16* vS = kS + elems;

    proj_kernel<<<B_SZ * NBLK, 256, 0, stream>>>(x, h, Wq, bq, Wk, bk, Wv, bv,
                                                 qS, kS, vS);
    attn_kernel<<<B_SZ * MTILES, 512, 0, stream>>>(qS, kS, vS, out);
}

// Round 6
// 104.583 us; speedup vs baseline: 1.8306x; 1.0197x over previous
//
#include <hip/hip_runtime.h>
#include <hip/hip_bf16.h>

#define C_DIM 64
#define N_TOK 4608
#define NBLK  72       // proj blocks per batch (64 tokens each)
#define B_SZ  2
#define MBLKS 144      // attn m-blocks per batch (32 m-tokens each)
#define NSEG  8        // n-segments == waves per attn block
#define SEGLEN (N_TOK / NSEG)   // 576
#define KTILES 288     // N_TOK/16 swizzled 16-token K/Q tiles per batch
#define VTILES 72      // N_TOK/64 swizzled 64-token V tiles per batch
#define OSTR  68       // o_lds padded stride (floats)

typedef __bf16 bf16x8 __attribute__((ext_vector_type(8)));
typedef float  f32x4  __attribute__((ext_vector_type(4)));

// ---------------------------------------------------------------------------
// Swizzled fragment layouts (16B-chunk granular, contiguous 1KB wave loads):
//  qS/kS: [b][ntile16][half=c>>5][quad=(c>>3)&3][col=n&15][e=c&7]
//  vS:    [b][ntile64][cc=c>>4][half=(n>>5)&1][quad=(n>>3)&3][col=c&15][e=n&7]
// ---------------------------------------------------------------------------

__device__ __forceinline__ void gemm_tile(
    const __hip_bfloat16* wmat, const bf16x8 bin[2], const float* bias,
    int col, int quad, f32x4 acc[4])
{
    #pragma unroll
    for (int ot = 0; ot < 4; ot++) {
        f32x4 a = (f32x4){0.f, 0.f, 0.f, 0.f};
        #pragma unroll
        for (int kh = 0; kh < 2; kh++) {
            bf16x8 wf = *(const bf16x8*)(wmat + (ot * 16 + col) * 72 +
                                         kh * 32 + quad * 8);
            a = __builtin_amdgcn_mfma_f32_16x16x32_bf16(wf, bin[kh], a, 0, 0, 0);
        }
        float4 b4 = *(const float4*)(bias + ot * 16 + quad * 4);
        a[0] += b4.x; a[1] += b4.y; a[2] += b4.z; a[3] += b4.w;
        acc[ot] = a;
    }
}

__device__ __forceinline__ void store_swz(
    __hip_bfloat16* dst, const f32x4 acc[4], int col, int quad, float sc)
{
    #pragma unroll
    for (int ot = 0; ot < 4; ot++) {
        union { __hip_bfloat16 e[4]; uint2 v; } pk;
        #pragma unroll
        for (int r = 0; r < 4; r++) pk.e[r] = __float2bfloat16(acc[ot][r] * sc);
        *(uint2*)(dst + (ot >> 1) * 512 + ((ot * 2 + (quad >> 1)) & 3) * 128 +
                  col * 8 + (quad & 1) * 4) = pk.v;
    }
}

// ---------------------------------------------------------------------------
// MFMA projection kernel. 256 threads (4 waves), 64 tokens per block.
// Fully vectorized global staging; all GEMM operands via ds_read_b128.
// ---------------------------------------------------------------------------
__global__ __launch_bounds__(256) void proj_kernel(
    const float* __restrict__ x,  const float* __restrict__ h,
    const float* __restrict__ Wq, const float* __restrict__ bq,
    const float* __restrict__ Wk, const float* __restrict__ bk,
    const float* __restrict__ Wv, const float* __restrict__ bv,
    __hip_bfloat16* __restrict__ qS, __hip_bfloat16* __restrict__ kS,
    __hip_bfloat16* __restrict__ vS)
{
    __shared__ __hip_bfloat16 wl[3 * 64 * 72];   // Wq,Wk,Wv bf16 [o][c] pad72
    __shared__ __hip_bfloat16 xt[64 * 72];       // x^T bf16 [n][c] pad72
    __shared__ __hip_bfloat16 ht[64 * 72];       // h^T bf16 [n][c] pad72
    __shared__ __hip_bfloat16 vl[64 * 72];       // v staging [c][n] pad72

    const int b  = blockIdx.x / NBLK;
    const int n0 = (blockIdx.x % NBLK) * 64;
    const int t  = threadIdx.x;

    // ---- stage weights: float4 global loads -> uint2 (4xbf16) LDS writes ----
    #pragma unroll
    for (int mat = 0; mat < 3; mat++) {
        const float* W = (mat == 0) ? Wq : ((mat == 1) ? Wk : Wv);
        __hip_bfloat16* wd = wl + mat * (64 * 72);
        #pragma unroll
        for (int i = 0; i < 4; i++) {
            const int ch = i * 256 + t;          // 1024 float4 chunks
            const int o = ch >> 4, c0 = (ch & 15) * 4;
            float4 w4 = *(const float4*)(W + ch * 4);
            union { __hip_bfloat16 e[4]; uint2 v; } pk;
            pk.e[0] = __float2bfloat16(w4.x); pk.e[1] = __float2bfloat16(w4.y);
            pk.e[2] = __float2bfloat16(w4.z); pk.e[3] = __float2bfloat16(w4.w);
            *(uint2*)(wd + o * 72 + c0) = pk.v;
        }
    }
    // ---- stage x,h transposed: float4 loads, scalar LDS writes (2-way) ----
    #pragma unroll
    for (int i = 0; i < 4; i++) {
        const int ch = i * 256 + t;              // 1024 chunks per array
        const int c = ch >> 4, n4 = (ch & 15) * 4;
        float4 x4 = *(const float4*)(x + (size_t)(b * C_DIM + c) * N_TOK + n0 + n4);
        float4 h4 = *(const float4*)(h + (size_t)(b * C_DIM + c) * N_TOK + n0 + n4);
        xt[(n4 + 0) * 72 + c] = __float2bfloat16(x4.x);
        xt[(n4 + 1) * 72 + c] = __float2bfloat16(x4.y);
        xt[(n4 + 2) * 72 + c] = __float2bfloat16(x4.z);
        xt[(n4 + 3) * 72 + c] = __float2bfloat16(x4.w);
        ht[(n4 + 0) * 72 + c] = __float2bfloat16(h4.x);
        ht[(n4 + 1) * 72 + c] = __float2bfloat16(h4.y);
        ht[(n4 + 2) * 72 + c] = __float2bfloat16(h4.z);
        ht[(n4 + 3) * 72 + c] = __float2bfloat16(h4.w);
    }
    __syncthreads();

    const int wave = t >> 6, lane = t & 63;
    const int col = lane & 15, quad = lane >> 4;

    bf16x8 xb[2], hb[2];
    #pragma unroll
    for (int kh = 0; kh < 2; kh++) {
        xb[kh] = *(const bf16x8*)(xt + (wave * 16 + col) * 72 + kh * 32 + quad * 8);
        hb[kh] = *(const bf16x8*)(ht + (wave * 16 + col) * 72 + kh * 32 + quad * 8);
    }

    const size_t tile16 = (size_t)b * KTILES + (n0 >> 4) + wave;
    f32x4 acc[4];

    gemm_tile(wl + 0 * (64 * 72), xb, bq, col, quad, acc);
    store_swz(qS + (tile16 << 10), acc, col, quad, 0.125f * 1.44269504088896f);

    gemm_tile(wl + 1 * (64 * 72), hb, bk, col, quad, acc);
    store_swz(kS + (tile16 << 10), acc, col, quad, 1.0f);

    gemm_tile(wl + 2 * (64 * 72), hb, bv, col, quad, acc);
    #pragma unroll
    for (int ot = 0; ot < 4; ot++)
        #pragma unroll
        for (int r = 0; r < 4; r++)
            vl[(ot * 16 + quad * 4 + r) * 72 + wave * 16 + col] =
                __float2bfloat16(acc[ot][r]);
    __syncthreads();
    {
        const size_t vbase = ((size_t)(b * VTILES) + (n0 >> 6)) << 12;
        #pragma unroll
        for (int rep = 0; rep < 2; rep++) {
            const int ch = rep * 256 + t;
            const int cc = ch >> 7, hf = (ch >> 6) & 1;
            const int qd = (ch >> 4) & 3, c2 = ch & 15;
            *(uint4*)(vS + vbase + (size_t)ch * 8) =
                *(const uint4*)(vl + (cc * 16 + c2) * 72 + hf * 32 + qd * 8);
        }
    }
}

// ---------------------------------------------------------------------------
// Flash attention. Block = 32 m-tokens; 8 waves each own 1/8 of n (576 tok)
// and BOTH 16-m subtiles, so every K/V fragment load is shared across 32 m
// (halves L2 traffic vs round 5). Two-phase LDS combine. grid = 288 x 512.
// ---------------------------------------------------------------------------
__global__ __launch_bounds__(512, 4) void attn_kernel(
    const __hip_bfloat16* __restrict__ qS,
    const __hip_bfloat16* __restrict__ kS,
    const __hip_bfloat16* __restrict__ vS,
    float* __restrict__ out)
{
    __shared__ __hip_bfloat16 plds[NSEG * 2 * 16 * 72];  // 2 P tiles / wave
    __shared__ float o_lds[NSEG * 16 * OSTR];            // one msub per phase
    __shared__ float mstat[NSEG][32];
    __shared__ float lstat[NSEG][32];

    const int b    = blockIdx.x / MBLKS;
    const int mblk = blockIdx.x % MBLKS;
    const int wave = threadIdx.x >> 6;
    const int lane = threadIdx.x & 63;
    const int col  = lane & 15;
    const int quad = lane >> 4;
    const int m0   = mblk * 32;

    __hip_bfloat16* pw0 = plds + wave * (2 * 16 * 72);
    __hip_bfloat16* pw1 = pw0 + 16 * 72;

    // loop-invariant Q fragments for both m-subtiles (contiguous 1KB loads)
    const __hip_bfloat16* qp =
        qS + (((size_t)b * KTILES + (m0 >> 4)) << 10) + lane * 8;
    const bf16x8 qa0 = *(const bf16x8*)(qp);
    const bf16x8 qa1 = *(const bf16x8*)(qp + 512);
    const bf16x8 qb0 = *(const bf16x8*)(qp + 1024);
    const bf16x8 qb1 = *(const bf16x8*)(qp + 1536);

    f32x4 accO0[4], accO1[4];
    #pragma unroll
    for (int cc = 0; cc < 4; cc++) {
        accO0[cc] = (f32x4){0.f, 0.f, 0.f, 0.f};
        accO1[cc] = (f32x4){0.f, 0.f, 0.f, 0.f};
    }
    float rmax0 = -3.0e38f, rsum0 = 0.f;
    float rmax1 = -3.0e38f, rsum1 = 0.f;

    const int nbeg = wave * SEGLEN;

    #pragma unroll 1
    for (int n0 = nbeg; n0 < nbeg + SEGLEN; n0 += 64) {
        // ---- K fragment loads (shared by both m-subtiles) ----
        const __hip_bfloat16* kt =
            kS + (((size_t)b * KTILES + (n0 >> 4)) << 10) + lane * 8;
        bf16x8 ka[8];
        #pragma unroll
        for (int j = 0; j < 4; j++) {
            ka[2 * j]     = *(const bf16x8*)(kt + (j << 10));
            ka[2 * j + 1] = *(const bf16x8*)(kt + (j << 10) + 512);
        }

        // ---- S^T tiles for both msubs ----
        f32x4 s0[4], s1[4];
        #pragma unroll
        for (int j = 0; j < 4; j++) {
            s0[j] = __builtin_amdgcn_mfma_f32_16x16x32_bf16(
                        ka[2 * j], qa0, (f32x4){0.f, 0.f, 0.f, 0.f}, 0, 0, 0);
            s0[j] = __builtin_amdgcn_mfma_f32_16x16x32_bf16(ka[2 * j + 1], qa1, s0[j], 0, 0, 0);
            s1[j] = __builtin_amdgcn_mfma_f32_16x16x32_bf16(
                        ka[2 * j], qb0, (f32x4){0.f, 0.f, 0.f, 0.f}, 0, 0, 0);
            s1[j] = __builtin_amdgcn_mfma_f32_16x16x32_bf16(ka[2 * j + 1], qb1, s1[j], 0, 0, 0);
        }

        // ---- softmax msub0 -> P0 ----
        {
            float tm = s0[0][0];
            #pragma unroll
            for (int j = 0; j < 4; j++)
                #pragma unroll
                for (int r = 0; r < 4; r++) tm = fmaxf(tm, s0[j][r]);
            tm = fmaxf(tm, __shfl_xor(tm, 16));
            tm = fmaxf(tm, __shfl_xor(tm, 32));
            const float nmax  = fmaxf(rmax0, tm);
            const float alpha = __builtin_amdgcn_exp2f(rmax0 - nmax);
            rmax0 = nmax;
            float psum = 0.f;
            #pragma unroll
            for (int j = 0; j < 4; j++) {
                union { __hip_bfloat16 e[4]; uint2 v; } pk;
                #pragma unroll
                for (int r = 0; r < 4; r++) {
                    float e = __builtin_amdgcn_exp2f(s0[j][r] - nmax);
                    psum += e;
                    pk.e[r] = __float2bfloat16(e);
                }
                *(uint2*)(pw0 + col * 72 + j * 16 + quad * 4) = pk.v;
            }
            rsum0 = rsum0 * alpha + psum;
            #pragma unroll
            for (int cc = 0; cc < 4; cc++)
                #pragma unroll
                for (int r = 0; r < 4; r++) accO0[cc][r] *= alpha;
        }
        // ---- softmax msub1 -> P1 ----
        {
            float tm = s1[0][0];
            #pragma unroll
            for (int j = 0; j < 4; j++)
                #pragma unroll
                for (int r = 0; r < 4; r++) tm = fmaxf(tm, s1[j][r]);
            tm = fmaxf(tm, __shfl_xor(tm, 16));
            tm = fmaxf(tm, __shfl_xor(tm, 32));
            const float nmax  = fmaxf(rmax1, tm);
            const float alpha = __builtin_amdgcn_exp2f(rmax1 - nmax);
            rmax1 = nmax;
            float psum = 0.f;
            #pragma unroll
            for (int j = 0; j < 4; j++) {
                union { __hip_bfloat16 e[4]; uint2 v; } pk;
                #pragma unroll
                for (int r = 0; r < 4; r++) {
                    float e = __builtin_amdgcn_exp2f(s1[j][r] - nmax);
                    psum += e;
                    pk.e[r] = __float2bfloat16(e);
                }
                *(uint2*)(pw1 + col * 72 + j * 16 + quad * 4) = pk.v;
            }
            rsum1 = rsum1 * alpha + psum;
            #pragma unroll
            for (int cc = 0; cc < 4; cc++)
                #pragma unroll
                for (int r = 0; r < 4; r++) accO1[cc][r] *= alpha;
        }

        // ---- V fragment loads (shared); issued before the lgkm drain ----
        const __hip_bfloat16* vt =
            vS + ((((size_t)b * VTILES) + (n0 >> 6)) << 12) + lane * 8;
        bf16x8 va[8];
        #pragma unroll
        for (int cc = 0; cc < 4; cc++) {
            va[2 * cc]     = *(const bf16x8*)(vt + cc * 1024);
            va[2 * cc + 1] = *(const bf16x8*)(vt + cc * 1024 + 512);
        }
        __asm__ volatile("s_waitcnt lgkmcnt(0)" ::: "memory");

        // ---- O^T += V . P^T for both msubs ----
        const bf16x8 p00 = *(const bf16x8*)(pw0 + col * 72 + quad * 8);
        const bf16x8 p01 = *(const bf16x8*)(pw0 + col * 72 + 32 + quad * 8);
        const bf16x8 p10 = *(const bf16x8*)(pw1 + col * 72 + quad * 8);
        const bf16x8 p11 = *(const bf16x8*)(pw1 + col * 72 + 32 + quad * 8);
        #pragma unroll
        for (int cc = 0; cc < 4; cc++) {
            accO0[cc] = __builtin_amdgcn_mfma_f32_16x16x32_bf16(va[2 * cc],     p00, accO0[cc], 0, 0, 0);
            accO0[cc] = __builtin_amdgcn_mfma_f32_16x16x32_bf16(va[2 * cc + 1], p01, accO0[cc], 0, 0, 0);
            accO1[cc] = __builtin_amdgcn_mfma_f32_16x16x32_bf16(va[2 * cc],     p10, accO1[cc], 0, 0, 0);
            accO1[cc] = __builtin_amdgcn_mfma_f32_16x16x32_bf16(va[2 * cc + 1], p11, accO1[cc], 0, 0, 0);
        }
    }

    // ---- finalize stats ----
    rsum0 += __shfl_xor(rsum0, 16);  rsum0 += __shfl_xor(rsum0, 32);
    rsum1 += __shfl_xor(rsum1, 16);  rsum1 += __shfl_xor(rsum1, 32);
    if (quad == 0) {
        mstat[wave][col]      = rmax0;  lstat[wave][col]      = rsum0;
        mstat[wave][16 + col] = rmax1;  lstat[wave][16 + col] = rsum1;
    }

    // ---- two-phase combine over 8 segments (reuses o_lds) ----
    #pragma unroll
    for (int phase = 0; phase < 2; phase++) {
        const f32x4* accp = phase ? accO1 : accO0;
        #pragma unroll
        for (int cc = 0; cc < 4; cc++)
            *(f32x4*)(o_lds + (wave * 16 + col) * OSTR + cc * 16 + quad * 4) =
                accp[cc];
        __syncthreads();
        if (threadIdx.x < 256) {
            const int m  = threadIdx.x & 15;
            const int cq = threadIdx.x >> 4;
            const int mi = phase * 16 + m;
            float M = -3.0e38f;
            #pragma unroll
            for (int sgm = 0; sgm < NSEG; sgm++) M = fmaxf(M, mstat[sgm][mi]);
            float lsum = 0.f;
            f32x4 oacc = (f32x4){0.f, 0.f, 0.f, 0.f};
            #pragma unroll
            for (int sgm = 0; sgm < NSEG; sgm++) {
                const float w = __builtin_amdgcn_exp2f(mstat[sgm][mi] - M);
                lsum += w * lstat[sgm][mi];
                oacc += w * *(const f32x4*)(o_lds + (sgm * 16 + m) * OSTR + cq * 4);
            }
            const float inv = 1.0f / lsum;
            #pragma unroll
            for (int r = 0; r < 4; r++) {
                const int c = cq * 4 + r;
                out[(size_t)(b * C_DIM + c) * N_TOK + m0 + phase * 16 + m] =
                    oacc[r] * inv;
            }
        }
        __syncthreads();
    }
}

extern "C" void kernel_launch(void* const* d_in, const int* in_sizes, int n_in,
                              void* d_out, int out_size, void* d_ws, size_t ws_size,
                              hipStream_t stream) {
    const float* x  = (const float*)d_in[0];
    const float* h  = (const float*)d_in[1];
    const float* Wq = (const float*)d_in[2];
    const float* bq = (const float*)d_in[3];
    const float* Wk = (const float*)d_in[4];
    const float* bk = (const float*)d_in[5];
    const float* Wv = (const float*)d_in[6];
    const float* bv = (const float*)d_in[7];
    float* out = (float*)d_out;

    const size_t elems = (size_t)B_SZ * N_TOK * C_DIM;   // 589824
    __hip_bfloat16* qS = (__hip_bfloat16*)d_ws;
    __hip_bfloat16* kS = qS + elems;
    __hip_bfloat16* vS = kS + elems;

    proj_kernel<<<B_SZ * NBLK, 256, 0, stream>>>(x, h, Wq, bq, Wk, bk, Wv, bv,
                                                 qS, kS, vS);
    attn_kernel<<<B_SZ * MBLKS, 512, 0, stream>>>(qS, kS, vS, out);
}